// Round 20
// baseline (227.468 us; speedup 1.0000x reference)
//
#include <hip/hip_runtime.h>
#include <hip/hip_bf16.h>

#define D 32

typedef const float* fp;
typedef unsigned short u16;
typedef unsigned int u32;

using short8 = __attribute__((ext_vector_type(8))) short;
using f32x4  = __attribute__((ext_vector_type(4))) float;

__device__ __forceinline__ float b2f(u32 lo16) { return __uint_as_float(lo16 << 16); }
__device__ __forceinline__ u16 f2b(float f) {
    u32 x = __float_as_uint(f);
    return (u16)((x + 0x7fffu + ((x >> 16) & 1u)) >> 16);   // RNE
}

// h (f32+bf16), u, v, B0 from x; P precomposed in LDS; zeroes a/cnt/cursor;
// blocks 0..255 also build the W2 MFMA-fragment table.
__global__ void k_hev(fp x, fp W_emb, fp b_emb, fp Wth, fp bth, fp Wph, fp bph,
                      fp W2, u16* __restrict__ W2f, fp b2,
                      float* __restrict__ h, u16* __restrict__ hbf,
                      float* __restrict__ u, float* __restrict__ v,
                      float* __restrict__ B, float* __restrict__ a,
                      int* __restrict__ cnt, int* __restrict__ cursor,
                      int Npad, int N) {
    __shared__ float sP[192];
    __shared__ float shh[8][D];
    __shared__ float sb2[1024];
    int tid = threadIdx.x;
    if (tid < 32) {
        int o = tid;
        float au0 = 0.f, au1 = 0.f, cu = 0.f, av0 = 0.f, av1 = 0.f, cv = 0.f;
        for (int i = 0; i < D; ++i) {
            float wt = Wth[i * D + o];
            float wd = Wph[i * D + o] - wt;
            au0 += W_emb[i] * wt;
            au1 += W_emb[D + i] * wt;
            cu  += b_emb[i] * wt;
            av0 += W_emb[i] * wd;
            av1 += W_emb[D + i] * wd;
            cv  += b_emb[i] * wd;
        }
        sP[o]       = au0;
        sP[32 + o]  = au1;
        sP[64 + o]  = cu + bth[o] + bph[o];
        sP[96 + o]  = av0;
        sP[128 + o] = av1;
        sP[160 + o] = cv;
    }
    if (blockIdx.x < 256) {
        int idx = blockIdx.x * 256 + tid;
        int T = idx >> 9, r = idx & 511, l = r >> 3, j = r & 7;
        int ko = T * 16 + (l & 15);
        int i = (l >> 4) * 8 + j;
        W2f[idx] = f2b(W2[(size_t)(ko >> 5) * 1024 + i * 32 + (ko & 31)]);
    }
    for (int i = tid; i < 1024; i += 256) sb2[i] = b2[i];
    __syncthreads();
    int t = blockIdx.x * 256 + tid;
    bool active = (t < N * D);
    int n = t >> 5, o = t & 31;
    if (active) {
        a[t] = 0.f;
        if (t < Npad) cnt[t] = 0;
        if (t < N) cursor[t] = 0;
        float x0 = x[2 * n], x1 = x[2 * n + 1];
        float hv = x0 * W_emb[o] + x1 * W_emb[D + o] + b_emb[o];
        h[t] = hv;
        hbf[t] = f2b(hv);
        shh[tid >> 5][o] = hv;
        u[t] = x0 * sP[o] + x1 * sP[32 + o] + sP[64 + o];
        v[t] = x0 * sP[96 + o] + x1 * sP[128 + o] + sP[160 + o];
    }
    __syncthreads();
    if (active) {
        int lr = tid >> 5;
        float acc = 0.f;
        #pragma unroll 8
        for (int i = 0; i < D; ++i) acc += shh[lr][i] * sb2[i * 32 + o];
        B[t] = acc;
    }
}

__global__ void k_count(const int* __restrict__ src, int* __restrict__ cnt, int E) {
    int e = blockIdx.x * 256 + threadIdx.x;
    if (e < E) atomicAdd(&cnt[src[e]], 1);
}

// dual exclusive scan (roff, toff) + inline tile-list generation
__global__ void k_scan(const int* __restrict__ cnt, int* __restrict__ roff,
                       int* __restrict__ toff, int* __restrict__ tilS,
                       int* __restrict__ tilB, int N) {
    __shared__ int pe[1024], pt[1024];
    int t = threadIdx.x;
    int per = (N + 1023) / 1024;
    int begin = t * per, end = min(begin + per, N);
    int se = 0, st = 0;
    for (int i = begin; i < end; ++i) { int c = cnt[i]; se += c; st += (c + 15) >> 4; }
    pe[t] = se; pt[t] = st;
    __syncthreads();
    for (int off = 1; off < 1024; off <<= 1) {
        int ve = (t >= off) ? pe[t - off] : 0;
        int vt = (t >= off) ? pt[t - off] : 0;
        __syncthreads();
        pe[t] += ve; pt[t] += vt;
        __syncthreads();
    }
    int pre_e = (t == 0) ? 0 : pe[t - 1];
    int pre_t = (t == 0) ? 0 : pt[t - 1];
    for (int i = begin; i < end; ++i) {
        int c = cnt[i];
        roff[i] = pre_e;
        toff[i] = pre_t;
        int nt2 = (c + 15) >> 4;
        for (int q = 0; q < nt2; ++q) { tilS[pre_t + q] = i; tilB[pre_t + q] = pre_e + 16 * q; }
        pre_e += c;
        pre_t += nt2;
    }
    if (t == 0) { roff[N] = pe[1023]; toff[N] = pt[1023]; }
}

__global__ void k_scatter(const int* __restrict__ src, const int* __restrict__ dst,
                          const int* __restrict__ roff, int* __restrict__ cursor,
                          int* __restrict__ ssrc, int* __restrict__ sdst, int E) {
    int e = blockIdx.x * 256 + threadIdx.x;
    if (e >= E) return;
    int s = src[e];
    int p = roff[s] + atomicAdd(&cursor[s], 1);
    ssrc[p] = s;
    sdst[p] = dst[e];
}

// barrier-free edge kernel: 8 independent waves; W1 columns (2o,2o+1) held in
// 64 per-lane VGPRs (loaded once); she broadcast via LDS with wave-local fence.
__global__ __launch_bounds__(512)
void k_edge2(const float* __restrict__ u, const float* __restrict__ v,
             const int* __restrict__ ssrc, const int* __restrict__ sdst,
             fp W1, fp b1, u16* __restrict__ g, int E) {
    __shared__ float she[8][2][D];
    int w = threadIdx.x >> 6, lane = threadIdx.x & 63;
    int sub = lane >> 5, o = lane & 31;
    // per-lane W1 slice: columns 2o and 2o+1 (fixed for this lane)
    float2 w1r[D];
    #pragma unroll
    for (int i = 0; i < D; ++i)
        w1r[i] = *(const float2*)(W1 + i * 64 + 2 * o);
    float bb0 = b1[2 * o], bb1 = b1[2 * o + 1];
    int gw = blockIdx.x * 8 + w;
    int stride = gridDim.x * 16;
    for (int e0 = gw * 2; e0 < E; e0 += stride) {
        int e = e0 + sub;
        bool val = (e < E);
        if (val) {
            int s = ssrc[e], d2 = sdst[e];
            she[w][sub][o] = fmaxf(u[(size_t)d2 * D + o] + v[(size_t)s * D + o], 0.f);
        }
        asm volatile("s_waitcnt lgkmcnt(0)" ::: "memory");
        __builtin_amdgcn_sched_barrier(0);
        if (val) {
            float a0 = bb0, a1 = bb1;
            #pragma unroll
            for (int i = 0; i < D; ++i) {
                float hv = she[w][sub][i];
                a0 += hv * w1r[i].x;
                a1 += hv * w1r[i].y;
            }
            ((u32*)g)[(size_t)e * 32 + o] =
                (u32)f2b(fmaxf(a0, 0.f)) | ((u32)f2b(fmaxf(a1, 0.f)) << 16);
        }
    }
}

// Fused M+msg: block = 16 srcs, 1024 threads (16 waves → 32 waves/CU at 2 blocks).
__global__ __launch_bounds__(1024, 2)
void k_msgf(const u16* __restrict__ hbf, const u16* __restrict__ W2f,
            const float* __restrict__ Bv, const u32* __restrict__ g32,
            const int* __restrict__ tilS, const int* __restrict__ tilB,
            const int* __restrict__ roff, const int* __restrict__ toff,
            const int* __restrict__ sdst, float* __restrict__ a, int N) {
    __shared__ u32 sfrag[16 * 1024];    // 64 KB: 16 srcs x 1024 u32
    int s0 = blockIdx.x * 16;
    int w = threadIdx.x >> 6, lp = threadIdx.x & 63;

    // ---- phase 1: wave w owns k = 4w, 4w+2 (pairs via ca/cb) ----
    {
        int arow = s0 + (lp & 15);
        if (arow >= N) arow = N - 1;
        short8 afrag = *(const short8*)(hbf + (size_t)arow * 32 + (lp >> 4) * 8);
        int rbase = (lp >> 4) * 4;
        #pragma unroll
        for (int mi = 0; mi < 2; ++mi) {
            int k = w * 4 + 2 * mi;
            int kh = k >> 5;
            int kp = k & 31;
            int lt = ((kp >> 3) << 4) | (lp & 15);
            int jp = (kp & 7) >> 1;
            #pragma unroll
            for (int ot = 0; ot < 2; ++ot) {
                int T = 2 * k + ot;
                short8 bA = *(const short8*)(W2f + (size_t)T * 512 + lp * 8);
                short8 bB = *(const short8*)(W2f + (size_t)(T + 2) * 512 + lp * 8);
                f32x4 ca{0.f,0.f,0.f,0.f}, cb{0.f,0.f,0.f,0.f};
                ca = __builtin_amdgcn_mfma_f32_16x16x32_bf16(afrag, bA, ca, 0, 0, 0);
                cb = __builtin_amdgcn_mfma_f32_16x16x32_bf16(afrag, bB, cb, 0, 0, 0);
                int idx = (((kh << 1) | ot) << 8) + lt * 4 + jp;
                #pragma unroll
                for (int r = 0; r < 4; ++r)
                    sfrag[((rbase + r) << 10) + idx] =
                        (u32)f2b(ca[r]) | ((u32)f2b(cb[r]) << 16);
            }
        }
    }
    __syncthreads();

    // ---- phase 2: message tiles (stride 16), pipelined prefetch ----
    int oc = lp & 15;
    int tbeg = toff[s0];
    int tend = toff[min(s0 + 16, N)];
    int ti = tbeg + w;
    uint4 A0c = make_uint4(0,0,0,0), A1c = A0c;
    int sC = 0, begC = 0, endC = 0;
    float Bs0c = 0.f, Bs1c = 0.f;
    if (ti < tend) {
        sC = tilS[ti]; begC = tilB[ti]; endC = roff[sC + 1];
        Bs0c = Bv[(size_t)sC * 32 + oc];
        Bs1c = Bv[(size_t)sC * 32 + 16 + oc];
        int er = begC + (lp & 15);
        if (er < endC) {
            const uint4* gp = (const uint4*)(g32 + (size_t)er * 32);
            A0c = gp[lp >> 4];
            A1c = gp[4 + (lp >> 4)];
        }
    }
    while (ti < tend) {
        int tn = ti + 16;
        uint4 A0n = make_uint4(0,0,0,0), A1n = A0n;
        int sN = 0, begN = 0, endN = 0;
        float Bs0n = 0.f, Bs1n = 0.f;
        if (tn < tend) {
            sN = tilS[tn]; begN = tilB[tn]; endN = roff[sN + 1];
            Bs0n = Bv[(size_t)sN * 32 + oc];
            Bs1n = Bv[(size_t)sN * 32 + 16 + oc];
            int er = begN + (lp & 15);
            if (er < endN) {
                const uint4* gp = (const uint4*)(g32 + (size_t)er * 32);
                A0n = gp[lp >> 4];
                A1n = gp[4 + (lp >> 4)];
            }
        }
        {
            union { uint4 u; short8 v; } A0, A1;
            A0.u = A0c; A1.u = A1c;
            const u32* mb = sfrag + ((sC - s0) << 10);
            union { uint4 u; short8 v; } B00, B01, B10, B11;
            B00.u = *(const uint4*)(mb + lp * 4);
            B01.u = *(const uint4*)(mb + 256 + lp * 4);
            B10.u = *(const uint4*)(mb + 512 + lp * 4);
            B11.u = *(const uint4*)(mb + 768 + lp * 4);
            f32x4 c0{0.f,0.f,0.f,0.f}, c1{0.f,0.f,0.f,0.f};
            __builtin_amdgcn_s_setprio(1);
            c0 = __builtin_amdgcn_mfma_f32_16x16x32_bf16(A0.v, B00.v, c0, 0, 0, 0);
            c0 = __builtin_amdgcn_mfma_f32_16x16x32_bf16(A1.v, B10.v, c0, 0, 0, 0);
            c1 = __builtin_amdgcn_mfma_f32_16x16x32_bf16(A0.v, B01.v, c1, 0, 0, 0);
            c1 = __builtin_amdgcn_mfma_f32_16x16x32_bf16(A1.v, B11.v, c1, 0, 0, 0);
            __builtin_amdgcn_s_setprio(0);
            int rb = (lp >> 4) * 4;
            #pragma unroll
            for (int r = 0; r < 4; ++r) {
                int e = begC + rb + r;
                if (e < endC) {
                    int d = sdst[e];
                    atomicAdd(&a[(size_t)d * 32 + oc],      c0[r] + Bs0c);
                    atomicAdd(&a[(size_t)d * 32 + 16 + oc], c1[r] + Bs1c);
                }
            }
        }
        ti = tn; sC = sN; begC = begN; endC = endN;
        A0c = A0n; A1c = A1n; Bs0c = Bs0n; Bs1c = Bs1n;
    }
}

// torch GRUCell, 8 nodes/block (1250 blocks ≈ 5/CU for latency hiding);
// zeroes a in place; writes f32+bf16 h AND next-step B in epilogue.
__global__ __launch_bounds__(256)
void k_gru(float* __restrict__ a, const float* __restrict__ h,
           fp W_ih, fp b_ih, fp W_hh, fp b_hh, fp b2,
           float* __restrict__ hout, u16* __restrict__ hbf,
           float* __restrict__ Bout, int N) {
    __shared__ float sWi[D * 96], sWh[D * 96], sbi[96], sbh[96];
    __shared__ float sa[8][D], sh[8][D];
    __shared__ float sb2[1024];
    for (int i = threadIdx.x; i < D * 96; i += 256) { sWi[i] = W_ih[i]; sWh[i] = W_hh[i]; }
    for (int i = threadIdx.x; i < 1024; i += 256) sb2[i] = b2[i];
    if (threadIdx.x < 96) { sbi[threadIdx.x] = b_ih[threadIdx.x]; sbh[threadIdx.x] = b_hh[threadIdx.x]; }
    int n0 = blockIdx.x * 8;
    for (int i = threadIdx.x; i < 8 * D; i += 256) {
        int n = n0 + (i >> 5);
        if (n < N) {
            size_t idx = (size_t)n * D + (i & 31);
            sa[i >> 5][i & 31] = a[idx];
            sh[i >> 5][i & 31] = h[idx];
            a[idx] = 0.f;
        }
    }
    __syncthreads();
    int sub = threadIdx.x >> 5, o = threadIdx.x & 31;
    int n = n0 + sub;
    if (n < N) {
        float ir = sbi[o], iz = sbi[D + o], in_ = sbi[2 * D + o];
        float hr = sbh[o], hz = sbh[D + o], hn = sbh[2 * D + o];
        #pragma unroll
        for (int i = 0; i < D; ++i) {
            float av = sa[sub][i], hv = sh[sub][i];
            ir += av * sWi[i * 96 + o];
            iz += av * sWi[i * 96 + D + o];
            in_ += av * sWi[i * 96 + 2 * D + o];
            hr += hv * sWh[i * 96 + o];
            hz += hv * sWh[i * 96 + D + o];
            hn += hv * sWh[i * 96 + 2 * D + o];
        }
        float r = 1.f / (1.f + __expf(-(ir + hr)));
        float zz = 1.f / (1.f + __expf(-(iz + hz)));
        float nn = tanhf(in_ + r * hn);
        float hv2 = (1.f - zz) * nn + zz * sh[sub][o];
        size_t idx = (size_t)n * D + o;
        hout[idx] = hv2;
        hbf[idx] = f2b(hv2);
        sa[sub][o] = hv2;     // wave-lockstep overwrite: this half-wave is row sub's only reader
    }
    __syncthreads();
    if (n < N) {
        float acc = 0.f;
        #pragma unroll 8
        for (int i = 0; i < D; ++i) acc += sa[sub][i] * sb2[i * 32 + o];
        Bout[(size_t)n * D + o] = acc;
    }
}

extern "C" void kernel_launch(void* const* d_in, const int* in_sizes, int n_in,
                              void* d_out, int out_size, void* d_ws, size_t ws_size,
                              hipStream_t stream) {
    fp x      = (fp)d_in[0];
    const int* src = (const int*)d_in[1];
    const int* dst = (const int*)d_in[2];
    fp W_emb  = (fp)d_in[3];
    fp b_emb  = (fp)d_in[4];
    fp W_th   = (fp)d_in[5];
    fp b_th   = (fp)d_in[6];
    fp W_ph   = (fp)d_in[7];
    fp b_ph   = (fp)d_in[8];
    fp W1     = (fp)d_in[9];
    fp b1     = (fp)d_in[10];
    fp W2     = (fp)d_in[11];
    fp b2     = (fp)d_in[12];
    fp W_ih   = (fp)d_in[13];
    fp b_ih   = (fp)d_in[14];
    fp W_hh   = (fp)d_in[15];
    fp b_hh   = (fp)d_in[16];

    const int N = in_sizes[0] / 2;
    const int E = in_sizes[1];
    const int Npad = N + 4 - (N % 4);
    const int maxTiles = N + (E + 15) / 16;

    float* a      = (float*)d_ws;                       // N*D f32
    int*   cnt    = (int*)(a + (size_t)N * D);          // Npad
    int*   cursor = cnt + Npad;                         // N
    int*   roff   = cursor + N;                         // Npad (N+1 used)
    int*   toff   = roff + Npad;                        // Npad (N+1 used)
    int*   ssrc   = toff + Npad;                        // E
    int*   sdst   = ssrc + E;                           // E
    int*   tilS   = sdst + E;                           // maxTiles
    int*   tilB   = tilS + maxTiles;                    // maxTiles
    float* hA     = (float*)(tilB + maxTiles);          // N*D
    float* hB     = hA + (size_t)N * D;                 // N*D
    u16*   g      = (u16*)(hB + (size_t)N * D);         // E*64 bf16
    u16*   hbf    = g + (size_t)E * 64;                 // N*D bf16
    u16*   W2f    = hbf + (size_t)N * D;                // 65536 bf16
    float* u      = (float*)(W2f + 65536);              // N*D
    float* v      = u + (size_t)N * D;                  // N*D
    float* B      = v + (size_t)N * D;                  // N*D

    int ndBlocks = (N * D + 255) / 256;
    int eBlocks  = (E + 255) / 256;

    k_hev<<<ndBlocks, 256, 0, stream>>>(x, W_emb, b_emb, W_th, b_th, W_ph, b_ph,
                                        W2, W2f, b2, hA, hbf, u, v, B,
                                        a, cnt, cursor, Npad, N);
    k_count<<<eBlocks, 256, 0, stream>>>(src, cnt, E);
    k_scan<<<1, 1024, 0, stream>>>(cnt, roff, toff, tilS, tilB, N);
    k_scatter<<<eBlocks, 256, 0, stream>>>(src, dst, roff, cursor, ssrc, sdst, E);
    k_edge2<<<2048, 512, 0, stream>>>(u, v, ssrc, sdst, W1, b1, g, E);

    int fBlocks = (N + 15) / 16;
    float* hc = hA;
    float* hn_ = hB;
    for (int step = 0; step < 3; ++step) {
        k_msgf<<<fBlocks, 1024, 0, stream>>>(hbf, W2f, B, (const u32*)g, tilS, tilB,
                                             roff, toff, sdst, a, N);
        float* dstbuf = (step == 2) ? (float*)d_out : hn_;
        k_gru<<<(N + 7) / 8, 256, 0, stream>>>(a, hc, W_ih, b_ih, W_hh, b_hh, b2,
                                               dstbuf, hbf, B, N);
        float* t = hc; hc = hn_; hn_ = t;
    }
}

// Round 21
// 223.784 us; speedup vs baseline: 1.0165x; 1.0165x over previous
//
#include <hip/hip_runtime.h>
#include <hip/hip_bf16.h>

#define D 32

typedef const float* fp;
typedef unsigned short u16;
typedef unsigned int u32;

using short8 = __attribute__((ext_vector_type(8))) short;
using f32x4  = __attribute__((ext_vector_type(4))) float;

__device__ __forceinline__ float b2f(u32 lo16) { return __uint_as_float(lo16 << 16); }
__device__ __forceinline__ u16 f2b(float f) {
    u32 x = __float_as_uint(f);
    return (u16)((x + 0x7fffu + ((x >> 16) & 1u)) >> 16);   // RNE
}

// h (f32+bf16), u, v, B0 from x; P precomposed in LDS; zeroes a/cnt/cursor;
// blocks 0..255 also build the W2 MFMA-fragment table.
__global__ void k_hev(fp x, fp W_emb, fp b_emb, fp Wth, fp bth, fp Wph, fp bph,
                      fp W2, u16* __restrict__ W2f, fp b2,
                      float* __restrict__ h, u16* __restrict__ hbf,
                      float* __restrict__ u, float* __restrict__ v,
                      float* __restrict__ B, float* __restrict__ a,
                      int* __restrict__ cnt, int* __restrict__ cursor,
                      int Npad, int N) {
    __shared__ float sP[192];
    __shared__ float shh[8][D];
    __shared__ float sb2[1024];
    int tid = threadIdx.x;
    if (tid < 32) {
        int o = tid;
        float au0 = 0.f, au1 = 0.f, cu = 0.f, av0 = 0.f, av1 = 0.f, cv = 0.f;
        for (int i = 0; i < D; ++i) {
            float wt = Wth[i * D + o];
            float wd = Wph[i * D + o] - wt;
            au0 += W_emb[i] * wt;
            au1 += W_emb[D + i] * wt;
            cu  += b_emb[i] * wt;
            av0 += W_emb[i] * wd;
            av1 += W_emb[D + i] * wd;
            cv  += b_emb[i] * wd;
        }
        sP[o]       = au0;
        sP[32 + o]  = au1;
        sP[64 + o]  = cu + bth[o] + bph[o];
        sP[96 + o]  = av0;
        sP[128 + o] = av1;
        sP[160 + o] = cv;
    }
    if (blockIdx.x < 256) {
        int idx = blockIdx.x * 256 + tid;
        int T = idx >> 9, r = idx & 511, l = r >> 3, j = r & 7;
        int ko = T * 16 + (l & 15);
        int i = (l >> 4) * 8 + j;
        W2f[idx] = f2b(W2[(size_t)(ko >> 5) * 1024 + i * 32 + (ko & 31)]);
    }
    for (int i = tid; i < 1024; i += 256) sb2[i] = b2[i];
    __syncthreads();
    int t = blockIdx.x * 256 + tid;
    bool active = (t < N * D);
    int n = t >> 5, o = t & 31;
    if (active) {
        a[t] = 0.f;
        if (t < Npad) cnt[t] = 0;
        if (t < N) cursor[t] = 0;
        float x0 = x[2 * n], x1 = x[2 * n + 1];
        float hv = x0 * W_emb[o] + x1 * W_emb[D + o] + b_emb[o];
        h[t] = hv;
        hbf[t] = f2b(hv);
        shh[tid >> 5][o] = hv;
        u[t] = x0 * sP[o] + x1 * sP[32 + o] + sP[64 + o];
        v[t] = x0 * sP[96 + o] + x1 * sP[128 + o] + sP[160 + o];
    }
    __syncthreads();
    if (active) {
        int lr = tid >> 5;
        float acc = 0.f;
        #pragma unroll 8
        for (int i = 0; i < D; ++i) acc += shh[lr][i] * sb2[i * 32 + o];
        B[t] = acc;
    }
}

__global__ void k_count(const int* __restrict__ src, int* __restrict__ cnt, int E) {
    int e = blockIdx.x * 256 + threadIdx.x;
    if (e < E) atomicAdd(&cnt[src[e]], 1);
}

// dual exclusive scan (roff, toff) + inline tile-list generation
__global__ void k_scan(const int* __restrict__ cnt, int* __restrict__ roff,
                       int* __restrict__ toff, int* __restrict__ tilS,
                       int* __restrict__ tilB, int N) {
    __shared__ int pe[1024], pt[1024];
    int t = threadIdx.x;
    int per = (N + 1023) / 1024;
    int begin = t * per, end = min(begin + per, N);
    int se = 0, st = 0;
    for (int i = begin; i < end; ++i) { int c = cnt[i]; se += c; st += (c + 15) >> 4; }
    pe[t] = se; pt[t] = st;
    __syncthreads();
    for (int off = 1; off < 1024; off <<= 1) {
        int ve = (t >= off) ? pe[t - off] : 0;
        int vt = (t >= off) ? pt[t - off] : 0;
        __syncthreads();
        pe[t] += ve; pt[t] += vt;
        __syncthreads();
    }
    int pre_e = (t == 0) ? 0 : pe[t - 1];
    int pre_t = (t == 0) ? 0 : pt[t - 1];
    for (int i = begin; i < end; ++i) {
        int c = cnt[i];
        roff[i] = pre_e;
        toff[i] = pre_t;
        int nt2 = (c + 15) >> 4;
        for (int q = 0; q < nt2; ++q) { tilS[pre_t + q] = i; tilB[pre_t + q] = pre_e + 16 * q; }
        pre_e += c;
        pre_t += nt2;
    }
    if (t == 0) { roff[N] = pe[1023]; toff[N] = pt[1023]; }
}

__global__ void k_scatter(const int* __restrict__ src, const int* __restrict__ dst,
                          const int* __restrict__ roff, int* __restrict__ cursor,
                          int* __restrict__ ssrc, int* __restrict__ sdst, int E) {
    int e = blockIdx.x * 256 + threadIdx.x;
    if (e >= E) return;
    int s = src[e];
    int p = roff[s] + atomicAdd(&cursor[s], 1);
    ssrc[p] = s;
    sdst[p] = dst[e];
}

// barrier-free edge kernel: 8 independent waves, wave-local lgkmcnt fences
__global__ __launch_bounds__(512)
void k_edge2(const float* __restrict__ u, const float* __restrict__ v,
             const int* __restrict__ ssrc, const int* __restrict__ sdst,
             fp W1, fp b1, u16* __restrict__ g, int E) {
    __shared__ float sW1[D * 64];
    __shared__ float sb1[64];
    __shared__ float she[8][2][D];
    for (int i = threadIdx.x; i < D * 64; i += 512) sW1[i] = W1[i];
    if (threadIdx.x < 64) sb1[threadIdx.x] = b1[threadIdx.x];
    __syncthreads();
    int w = threadIdx.x >> 6, lane = threadIdx.x & 63;
    int sub = lane >> 5, o = lane & 31;
    int gw = blockIdx.x * 8 + w;
    int stride = gridDim.x * 16;
    const float2* w2p = (const float2*)sW1;
    for (int e0 = gw * 2; e0 < E; e0 += stride) {
        int e = e0 + sub;
        bool val = (e < E);
        if (val) {
            int s = ssrc[e], d2 = sdst[e];
            she[w][sub][o] = fmaxf(u[(size_t)d2 * D + o] + v[(size_t)s * D + o], 0.f);
        }
        asm volatile("s_waitcnt lgkmcnt(0)" ::: "memory");
        __builtin_amdgcn_sched_barrier(0);
        if (val) {
            float a0 = sb1[2 * o], a1 = sb1[2 * o + 1];
            #pragma unroll
            for (int i = 0; i < D; ++i) {
                float hv = she[w][sub][i];
                float2 ww = w2p[i * 32 + o];
                a0 += hv * ww.x;
                a1 += hv * ww.y;
            }
            ((u32*)g)[(size_t)e * 32 + o] =
                (u32)f2b(fmaxf(a0, 0.f)) | ((u32)f2b(fmaxf(a1, 0.f)) << 16);
        }
        asm volatile("s_waitcnt lgkmcnt(0)" ::: "memory");
        __builtin_amdgcn_sched_barrier(0);
    }
}

// Fused M+msg: block = 16 srcs, 1024 threads (16 waves → 32 waves/CU at 2 blocks).
__global__ __launch_bounds__(1024, 2)
void k_msgf(const u16* __restrict__ hbf, const u16* __restrict__ W2f,
            const float* __restrict__ Bv, const u32* __restrict__ g32,
            const int* __restrict__ tilS, const int* __restrict__ tilB,
            const int* __restrict__ roff, const int* __restrict__ toff,
            const int* __restrict__ sdst, float* __restrict__ a, int N) {
    __shared__ u32 sfrag[16 * 1024];    // 64 KB: 16 srcs x 1024 u32
    int s0 = blockIdx.x * 16;
    int w = threadIdx.x >> 6, lp = threadIdx.x & 63;

    // ---- phase 1: wave w owns k = 4w, 4w+2 (pairs via ca/cb) ----
    {
        int arow = s0 + (lp & 15);
        if (arow >= N) arow = N - 1;
        short8 afrag = *(const short8*)(hbf + (size_t)arow * 32 + (lp >> 4) * 8);
        int rbase = (lp >> 4) * 4;
        #pragma unroll
        for (int mi = 0; mi < 2; ++mi) {
            int k = w * 4 + 2 * mi;
            int kh = k >> 5;
            int kp = k & 31;
            int lt = ((kp >> 3) << 4) | (lp & 15);
            int jp = (kp & 7) >> 1;
            #pragma unroll
            for (int ot = 0; ot < 2; ++ot) {
                int T = 2 * k + ot;
                short8 bA = *(const short8*)(W2f + (size_t)T * 512 + lp * 8);
                short8 bB = *(const short8*)(W2f + (size_t)(T + 2) * 512 + lp * 8);
                f32x4 ca{0.f,0.f,0.f,0.f}, cb{0.f,0.f,0.f,0.f};
                ca = __builtin_amdgcn_mfma_f32_16x16x32_bf16(afrag, bA, ca, 0, 0, 0);
                cb = __builtin_amdgcn_mfma_f32_16x16x32_bf16(afrag, bB, cb, 0, 0, 0);
                int idx = (((kh << 1) | ot) << 8) + lt * 4 + jp;
                #pragma unroll
                for (int r = 0; r < 4; ++r)
                    sfrag[((rbase + r) << 10) + idx] =
                        (u32)f2b(ca[r]) | ((u32)f2b(cb[r]) << 16);
            }
        }
    }
    __syncthreads();

    // ---- phase 2: message tiles (stride 16), pipelined prefetch ----
    int oc = lp & 15;
    int tbeg = toff[s0];
    int tend = toff[min(s0 + 16, N)];
    int ti = tbeg + w;
    uint4 A0c = make_uint4(0,0,0,0), A1c = A0c;
    int sC = 0, begC = 0, endC = 0;
    float Bs0c = 0.f, Bs1c = 0.f;
    if (ti < tend) {
        sC = tilS[ti]; begC = tilB[ti]; endC = roff[sC + 1];
        Bs0c = Bv[(size_t)sC * 32 + oc];
        Bs1c = Bv[(size_t)sC * 32 + 16 + oc];
        int er = begC + (lp & 15);
        if (er < endC) {
            const uint4* gp = (const uint4*)(g32 + (size_t)er * 32);
            A0c = gp[lp >> 4];
            A1c = gp[4 + (lp >> 4)];
        }
    }
    while (ti < tend) {
        int tn = ti + 16;
        uint4 A0n = make_uint4(0,0,0,0), A1n = A0n;
        int sN = 0, begN = 0, endN = 0;
        float Bs0n = 0.f, Bs1n = 0.f;
        if (tn < tend) {
            sN = tilS[tn]; begN = tilB[tn]; endN = roff[sN + 1];
            Bs0n = Bv[(size_t)sN * 32 + oc];
            Bs1n = Bv[(size_t)sN * 32 + 16 + oc];
            int er = begN + (lp & 15);
            if (er < endN) {
                const uint4* gp = (const uint4*)(g32 + (size_t)er * 32);
                A0n = gp[lp >> 4];
                A1n = gp[4 + (lp >> 4)];
            }
        }
        {
            union { uint4 u; short8 v; } A0, A1;
            A0.u = A0c; A1.u = A1c;
            const u32* mb = sfrag + ((sC - s0) << 10);
            union { uint4 u; short8 v; } B00, B01, B10, B11;
            B00.u = *(const uint4*)(mb + lp * 4);
            B01.u = *(const uint4*)(mb + 256 + lp * 4);
            B10.u = *(const uint4*)(mb + 512 + lp * 4);
            B11.u = *(const uint4*)(mb + 768 + lp * 4);
            f32x4 c0{0.f,0.f,0.f,0.f}, c1{0.f,0.f,0.f,0.f};
            __builtin_amdgcn_s_setprio(1);
            c0 = __builtin_amdgcn_mfma_f32_16x16x32_bf16(A0.v, B00.v, c0, 0, 0, 0);
            c0 = __builtin_amdgcn_mfma_f32_16x16x32_bf16(A1.v, B10.v, c0, 0, 0, 0);
            c1 = __builtin_amdgcn_mfma_f32_16x16x32_bf16(A0.v, B01.v, c1, 0, 0, 0);
            c1 = __builtin_amdgcn_mfma_f32_16x16x32_bf16(A1.v, B11.v, c1, 0, 0, 0);
            __builtin_amdgcn_s_setprio(0);
            int rb = (lp >> 4) * 4;
            #pragma unroll
            for (int r = 0; r < 4; ++r) {
                int e = begC + rb + r;
                if (e < endC) {
                    int d = sdst[e];
                    atomicAdd(&a[(size_t)d * 32 + oc],      c0[r] + Bs0c);
                    atomicAdd(&a[(size_t)d * 32 + 16 + oc], c1[r] + Bs1c);
                }
            }
        }
        ti = tn; sC = sN; begC = begN; endC = endN;
        A0c = A0n; A1c = A1n; Bs0c = Bs0n; Bs1c = Bs1n;
    }
}

// torch GRUCell, 8 nodes/block (1250 blocks ≈ 5/CU for latency hiding);
// zeroes a in place; writes f32+bf16 h AND next-step B in epilogue.
__global__ __launch_bounds__(256)
void k_gru(float* __restrict__ a, const float* __restrict__ h,
           fp W_ih, fp b_ih, fp W_hh, fp b_hh, fp b2,
           float* __restrict__ hout, u16* __restrict__ hbf,
           float* __restrict__ Bout, int N) {
    __shared__ float sWi[D * 96], sWh[D * 96], sbi[96], sbh[96];
    __shared__ float sa[8][D], sh[8][D];
    __shared__ float sb2[1024];
    for (int i = threadIdx.x; i < D * 96; i += 256) { sWi[i] = W_ih[i]; sWh[i] = W_hh[i]; }
    for (int i = threadIdx.x; i < 1024; i += 256) sb2[i] = b2[i];
    if (threadIdx.x < 96) { sbi[threadIdx.x] = b_ih[threadIdx.x]; sbh[threadIdx.x] = b_hh[threadIdx.x]; }
    int n0 = blockIdx.x * 8;
    for (int i = threadIdx.x; i < 8 * D; i += 256) {
        int n = n0 + (i >> 5);
        if (n < N) {
            size_t idx = (size_t)n * D + (i & 31);
            sa[i >> 5][i & 31] = a[idx];
            sh[i >> 5][i & 31] = h[idx];
            a[idx] = 0.f;
        }
    }
    __syncthreads();
    int sub = threadIdx.x >> 5, o = threadIdx.x & 31;
    int n = n0 + sub;
    if (n < N) {
        float ir = sbi[o], iz = sbi[D + o], in_ = sbi[2 * D + o];
        float hr = sbh[o], hz = sbh[D + o], hn = sbh[2 * D + o];
        #pragma unroll
        for (int i = 0; i < D; ++i) {
            float av = sa[sub][i], hv = sh[sub][i];
            ir += av * sWi[i * 96 + o];
            iz += av * sWi[i * 96 + D + o];
            in_ += av * sWi[i * 96 + 2 * D + o];
            hr += hv * sWh[i * 96 + o];
            hz += hv * sWh[i * 96 + D + o];
            hn += hv * sWh[i * 96 + 2 * D + o];
        }
        float r = 1.f / (1.f + __expf(-(ir + hr)));
        float zz = 1.f / (1.f + __expf(-(iz + hz)));
        float nn = tanhf(in_ + r * hn);
        float hv2 = (1.f - zz) * nn + zz * sh[sub][o];
        size_t idx = (size_t)n * D + o;
        hout[idx] = hv2;
        hbf[idx] = f2b(hv2);
        sa[sub][o] = hv2;     // wave-lockstep overwrite: this half-wave is row sub's only reader
    }
    __syncthreads();
    if (n < N) {
        float acc = 0.f;
        #pragma unroll 8
        for (int i = 0; i < D; ++i) acc += sa[sub][i] * sb2[i * 32 + o];
        Bout[(size_t)n * D + o] = acc;
    }
}

extern "C" void kernel_launch(void* const* d_in, const int* in_sizes, int n_in,
                              void* d_out, int out_size, void* d_ws, size_t ws_size,
                              hipStream_t stream) {
    fp x      = (fp)d_in[0];
    const int* src = (const int*)d_in[1];
    const int* dst = (const int*)d_in[2];
    fp W_emb  = (fp)d_in[3];
    fp b_emb  = (fp)d_in[4];
    fp W_th   = (fp)d_in[5];
    fp b_th   = (fp)d_in[6];
    fp W_ph   = (fp)d_in[7];
    fp b_ph   = (fp)d_in[8];
    fp W1     = (fp)d_in[9];
    fp b1     = (fp)d_in[10];
    fp W2     = (fp)d_in[11];
    fp b2     = (fp)d_in[12];
    fp W_ih   = (fp)d_in[13];
    fp b_ih   = (fp)d_in[14];
    fp W_hh   = (fp)d_in[15];
    fp b_hh   = (fp)d_in[16];

    const int N = in_sizes[0] / 2;
    const int E = in_sizes[1];
    const int Npad = N + 4 - (N % 4);
    const int maxTiles = N + (E + 15) / 16;

    float* a      = (float*)d_ws;                       // N*D f32
    int*   cnt    = (int*)(a + (size_t)N * D);          // Npad
    int*   cursor = cnt + Npad;                         // N
    int*   roff   = cursor + N;                         // Npad (N+1 used)
    int*   toff   = roff + Npad;                        // Npad (N+1 used)
    int*   ssrc   = toff + Npad;                        // E
    int*   sdst   = ssrc + E;                           // E
    int*   tilS   = sdst + E;                           // maxTiles
    int*   tilB   = tilS + maxTiles;                    // maxTiles
    float* hA     = (float*)(tilB + maxTiles);          // N*D
    float* hB     = hA + (size_t)N * D;                 // N*D
    u16*   g      = (u16*)(hB + (size_t)N * D);         // E*64 bf16
    u16*   hbf    = g + (size_t)E * 64;                 // N*D bf16
    u16*   W2f    = hbf + (size_t)N * D;                // 65536 bf16
    float* u      = (float*)(W2f + 65536);              // N*D
    float* v      = u + (size_t)N * D;                  // N*D
    float* B      = v + (size_t)N * D;                  // N*D

    int ndBlocks = (N * D + 255) / 256;
    int eBlocks  = (E + 255) / 256;

    k_hev<<<ndBlocks, 256, 0, stream>>>(x, W_emb, b_emb, W_th, b_th, W_ph, b_ph,
                                        W2, W2f, b2, hA, hbf, u, v, B,
                                        a, cnt, cursor, Npad, N);
    k_count<<<eBlocks, 256, 0, stream>>>(src, cnt, E);
    k_scan<<<1, 1024, 0, stream>>>(cnt, roff, toff, tilS, tilB, N);
    k_scatter<<<eBlocks, 256, 0, stream>>>(src, dst, roff, cursor, ssrc, sdst, E);
    k_edge2<<<2048, 512, 0, stream>>>(u, v, ssrc, sdst, W1, b1, g, E);

    int fBlocks = (N + 15) / 16;
    float* hc = hA;
    float* hn_ = hB;
    for (int step = 0; step < 3; ++step) {
        k_msgf<<<fBlocks, 1024, 0, stream>>>(hbf, W2f, B, (const u32*)g, tilS, tilB,
                                             roff, toff, sdst, a, N);
        float* dstbuf = (step == 2) ? (float*)d_out : hn_;
        k_gru<<<(N + 7) / 8, 256, 0, stream>>>(a, hc, W_ih, b_ih, W_hh, b_hh, b2,
                                               dstbuf, hbf, B, N);
        float* t = hc; hc = hn_; hn_ = t;
    }
}